// Round 12
// baseline (429.590 us; speedup 1.0000x reference)
//
#include <hip/hip_runtime.h>
#include <hip/hip_bf16.h>
#include <math.h>

#define CCH 256          // channels
#define ABLK 1024        // stage-1 reduction blocks
#define A2BLK 16         // stage-2 reduction blocks
#define ROWS 64          // rows per block in fused kernel

typedef float floatx4 __attribute__((ext_vector_type(4)));  // native clang vector for nontemporal builtin

__device__ __forceinline__ float wred_sum(float v) {
#pragma unroll
  for (int m = 32; m; m >>= 1) v += __shfl_xor(v, m, 64);
  return v;
}

// ---------------- Stage 1: column partial sums/maxes over rows -------------
__global__ __launch_bounds__(256) void k_colred(
    const float4* __restrict__ x4, float* __restrict__ psum,
    float* __restrict__ pmax, int N) {
  const int lane = threadIdx.x & 63;
  const int sr = threadIdx.x >> 6;  // 0..3 sub-row
  float4 s = make_float4(0.f, 0.f, 0.f, 0.f);
  float4 m = make_float4(-INFINITY, -INFINITY, -INFINITY, -INFINITY);
  for (int r = blockIdx.x * 4 + sr; r < N; r += gridDim.x * 4) {
    float4 v = x4[(size_t)r * 64 + lane];
    s.x += v.x; s.y += v.y; s.z += v.z; s.w += v.w;
    m.x = fmaxf(m.x, v.x); m.y = fmaxf(m.y, v.y);
    m.z = fmaxf(m.z, v.z); m.w = fmaxf(m.w, v.w);
  }
  __shared__ float4 ls[256], lm[256];
  ls[threadIdx.x] = s; lm[threadIdx.x] = m;
  __syncthreads();
  if (threadIdx.x < 64) {
    float4 s0 = ls[lane], s1 = ls[64 + lane], s2 = ls[128 + lane], s3 = ls[192 + lane];
    float4 m0 = lm[lane], m1 = lm[64 + lane], m2 = lm[128 + lane], m3 = lm[192 + lane];
    float4 so, mo;
    so.x = (s0.x + s1.x) + (s2.x + s3.x);
    so.y = (s0.y + s1.y) + (s2.y + s3.y);
    so.z = (s0.z + s1.z) + (s2.z + s3.z);
    so.w = (s0.w + s1.w) + (s2.w + s3.w);
    mo.x = fmaxf(fmaxf(m0.x, m1.x), fmaxf(m2.x, m3.x));
    mo.y = fmaxf(fmaxf(m0.y, m1.y), fmaxf(m2.y, m3.y));
    mo.z = fmaxf(fmaxf(m0.z, m1.z), fmaxf(m2.z, m3.z));
    mo.w = fmaxf(fmaxf(m0.w, m1.w), fmaxf(m2.w, m3.w));
    ((float4*)psum)[(size_t)blockIdx.x * 64 + lane] = so;
    ((float4*)pmax)[(size_t)blockIdx.x * 64 + lane] = mo;
  }
}

// ---------------- Stage 2: 1024 partials -> 16 partials --------------------
__global__ __launch_bounds__(256) void k_colred2(
    const float* __restrict__ psum, const float* __restrict__ pmax,
    float* __restrict__ s2sum, float* __restrict__ s2max) {
  const int lane = threadIdx.x & 63;
  const int sr = threadIdx.x >> 6;
  const int base = blockIdx.x * (ABLK / A2BLK);
  float4 s = make_float4(0.f, 0.f, 0.f, 0.f);
  float4 m = make_float4(-INFINITY, -INFINITY, -INFINITY, -INFINITY);
  for (int p = base + sr; p < base + (ABLK / A2BLK); p += 4) {
    float4 v = ((const float4*)psum)[(size_t)p * 64 + lane];
    s.x += v.x; s.y += v.y; s.z += v.z; s.w += v.w;
    float4 w = ((const float4*)pmax)[(size_t)p * 64 + lane];
    m.x = fmaxf(m.x, w.x); m.y = fmaxf(m.y, w.y);
    m.z = fmaxf(m.z, w.z); m.w = fmaxf(m.w, w.w);
  }
  __shared__ float4 ls[256], lm[256];
  ls[threadIdx.x] = s; lm[threadIdx.x] = m;
  __syncthreads();
  if (threadIdx.x < 64) {
    float4 s0 = ls[lane], s1 = ls[64 + lane], s2 = ls[128 + lane], s3 = ls[192 + lane];
    float4 m0 = lm[lane], m1 = lm[64 + lane], m2 = lm[128 + lane], m3 = lm[192 + lane];
    float4 so, mo;
    so.x = (s0.x + s1.x) + (s2.x + s3.x);
    so.y = (s0.y + s1.y) + (s2.y + s3.y);
    so.z = (s0.z + s1.z) + (s2.z + s3.z);
    so.w = (s0.w + s1.w) + (s2.w + s3.w);
    mo.x = fmaxf(fmaxf(m0.x, m1.x), fmaxf(m2.x, m3.x));
    mo.y = fmaxf(fmaxf(m0.y, m1.y), fmaxf(m2.y, m3.y));
    mo.z = fmaxf(fmaxf(m0.z, m1.z), fmaxf(m2.z, m3.z));
    mo.w = fmaxf(fmaxf(m0.w, m1.w), fmaxf(m2.w, m3.w));
    ((float4*)s2sum)[(size_t)blockIdx.x * 64 + lane] = so;
    ((float4*)s2max)[(size_t)blockIdx.x * 64 + lane] = mo;
  }
}

// ---------------- Stage 3: finish reduction + channel-attention MLP --------
__global__ __launch_bounds__(256) void k_att(
    const float* __restrict__ s2sum, const float* __restrict__ s2max,
    const float* __restrict__ w1, const float* __restrict__ w2,
    float* __restrict__ att, int N) {
  __shared__ float vec[2][CCH];   // [0]=avg, [1]=max
  __shared__ float hid[2][32];
  __shared__ float4 ls[256], lm[256];
  const int tid = threadIdx.x;
  const int lane = tid & 63;
  const int sr = tid >> 6;
  float4 s = make_float4(0.f, 0.f, 0.f, 0.f);
  float4 m = make_float4(-INFINITY, -INFINITY, -INFINITY, -INFINITY);
  for (int p = sr; p < A2BLK; p += 4) {
    float4 v = ((const float4*)s2sum)[(size_t)p * 64 + lane];
    s.x += v.x; s.y += v.y; s.z += v.z; s.w += v.w;
    float4 w = ((const float4*)s2max)[(size_t)p * 64 + lane];
    m.x = fmaxf(m.x, w.x); m.y = fmaxf(m.y, w.y);
    m.z = fmaxf(m.z, w.z); m.w = fmaxf(m.w, w.w);
  }
  ls[tid] = s; lm[tid] = m;
  __syncthreads();
  if (tid < 64) {
    float4 s0 = ls[lane], s1 = ls[64 + lane], s2 = ls[128 + lane], s3 = ls[192 + lane];
    float4 m0 = lm[lane], m1 = lm[64 + lane], m2 = lm[128 + lane], m3 = lm[192 + lane];
    float inv = 1.f / (float)N;
    vec[0][4 * lane + 0] = ((s0.x + s1.x) + (s2.x + s3.x)) * inv;
    vec[0][4 * lane + 1] = ((s0.y + s1.y) + (s2.y + s3.y)) * inv;
    vec[0][4 * lane + 2] = ((s0.z + s1.z) + (s2.z + s3.z)) * inv;
    vec[0][4 * lane + 3] = ((s0.w + s1.w) + (s2.w + s3.w)) * inv;
    vec[1][4 * lane + 0] = fmaxf(fmaxf(m0.x, m1.x), fmaxf(m2.x, m3.x));
    vec[1][4 * lane + 1] = fmaxf(fmaxf(m0.y, m1.y), fmaxf(m2.y, m3.y));
    vec[1][4 * lane + 2] = fmaxf(fmaxf(m0.z, m1.z), fmaxf(m2.z, m3.z));
    vec[1][4 * lane + 3] = fmaxf(fmaxf(m0.w, m1.w), fmaxf(m2.w, m3.w));
  }
  __syncthreads();
  // hidden layer: h[which][j] = relu(dot(vec[which], w1[j,:]))
  if (tid < 64) {
    const int which = tid >> 5;
    const int j = tid & 31;
    float acc = 0.f;
    for (int c = 0; c < CCH; ++c) acc += vec[which][c] * w1[j * CCH + c];
    hid[which][j] = fmaxf(acc, 0.f);
  }
  __syncthreads();
  // output layer + sigmoid: att[c] = sigmoid(sum_j (ha[j]+hm[j]) * w2[c,j])
  {
    const int c = tid;
    float acc = 0.f;
#pragma unroll
    for (int j = 0; j < 32; ++j) acc += (hid[0][j] + hid[1][j]) * w2[c * 32 + j];
    att[c] = 1.f / (1.f + expf(-acc));
  }
}

// ---------------- Stage 4: fused LN + spatial attention + output -----------
__global__ __launch_bounds__(256) void k_fused(
    const float4* __restrict__ x4, const float* __restrict__ att,
    const float* __restrict__ ln_g, const float* __restrict__ ln_b,
    const float* __restrict__ conv_w, const float* __restrict__ gamma,
    float4* __restrict__ out4, int N) {
  const int lane = threadIdx.x & 63;
  const int wid = threadIdx.x >> 6;  // wave id 0..3, one wave per row
  const float4 ac = ((const float4*)att)[lane];
  const float4 g4 = ((const float4*)ln_g)[lane];
  const float4 b4 = ((const float4*)ln_b)[lane];
  float cw0 = conv_w[0], cw1 = conv_w[1], cw2 = conv_w[2];
  float cw3 = conv_w[3], cw4 = conv_w[4], cw5 = conv_w[5];
  const float gm = gamma[0];
  __shared__ float a_s[ROWS + 2], m_s[ROWS + 2];
  const int r0 = blockIdx.x * ROWS;

  // phase 1: per-row (incl. halo rows r0-1 and r0+ROWS) compute a, m
  for (int i = wid; i < ROWS + 2; i += 4) {
    const int gr = r0 - 1 + i;
    float asum = 0.f, amax = 0.f;  // zero-padding for out-of-range rows
    if (gr >= 0 && gr < N) {
      float4 v = x4[(size_t)gr * 64 + lane];
      v.x *= ac.x; v.y *= ac.y; v.z *= ac.z; v.w *= ac.w;
      float rsum = (v.x + v.y) + (v.z + v.w);
      rsum = wred_sum(rsum);
      const float mu = rsum * (1.f / 256.f);
      const float dx = v.x - mu, dy = v.y - mu, dz = v.z - mu, dw = v.w - mu;
      float ssq = (dx * dx + dy * dy) + (dz * dz + dw * dw);
      ssq = wred_sum(ssq);
      const float rs = rsqrtf(ssq * (1.f / 256.f) + 1e-5f);
      const float n0 = dx * rs * g4.x + b4.x;
      const float n1 = dy * rs * g4.y + b4.y;
      const float n2 = dz * rs * g4.z + b4.z;
      const float n3 = dw * rs * g4.w + b4.w;
      float xs = (n0 + n1) + (n2 + n3);
      float xm = fmaxf(fmaxf(n0, n1), fmaxf(n2, n3));
#pragma unroll
      for (int msk = 32; msk; msk >>= 1) {
        xs += __shfl_xor(xs, msk, 64);
        xm = fmaxf(xm, __shfl_xor(xm, msk, 64));
      }
      asum = xs * (1.f / 256.f);
      amax = xm;
    }
    if (lane == 0) { a_s[i] = asum; m_s[i] = amax; }
  }
  __syncthreads();

  // phase 2: conv over node-neighbors + sigmoid + scaled output
  for (int i = wid; i < ROWS; i += 4) {
    const int gr = r0 + i;
    if (gr >= N) break;
    const float z = a_s[i] * cw0 + a_s[i + 1] * cw1 + a_s[i + 2] * cw2 +
                    m_s[i] * cw3 + m_s[i + 1] * cw4 + m_s[i + 2] * cw5;
    const float sg = 1.f / (1.f + expf(-z));
    const float scale = 1.f + gm * sg;
    float4 v = x4[(size_t)gr * 64 + lane];
    floatx4 o;
    o.x = v.x * ac.x * scale;
    o.y = v.y * ac.y * scale;
    o.z = v.z * ac.z * scale;
    o.w = v.w * ac.w * scale;
    __builtin_nontemporal_store(o, (floatx4*)&out4[(size_t)gr * 64 + lane]);
  }
}

extern "C" void kernel_launch(void* const* d_in, const int* in_sizes, int n_in,
                              void* d_out, int out_size, void* d_ws, size_t ws_size,
                              hipStream_t stream) {
  const float* x = (const float*)d_in[0];
  const float* w1 = (const float*)d_in[1];
  const float* w2 = (const float*)d_in[2];
  const float* conv_w = (const float*)d_in[3];
  const float* ln_g = (const float*)d_in[4];
  const float* ln_b = (const float*)d_in[5];
  const float* gamma = (const float*)d_in[6];
  float* out = (float*)d_out;
  const int N = in_sizes[0] / CCH;

  float* psum = (float*)d_ws;                          // ABLK*CCH
  float* pmax = psum + (size_t)ABLK * CCH;             // ABLK*CCH
  float* s2sum = pmax + (size_t)ABLK * CCH;            // A2BLK*CCH
  float* s2max = s2sum + (size_t)A2BLK * CCH;          // A2BLK*CCH
  float* att = s2max + (size_t)A2BLK * CCH;            // CCH

  k_colred<<<ABLK, 256, 0, stream>>>((const float4*)x, psum, pmax, N);
  k_colred2<<<A2BLK, 256, 0, stream>>>(psum, pmax, s2sum, s2max);
  k_att<<<1, 256, 0, stream>>>(s2sum, s2max, w1, w2, att, N);
  const int cblocks = (N + ROWS - 1) / ROWS;
  k_fused<<<cblocks, 256, 0, stream>>>((const float4*)x, att, ln_g, ln_b,
                                       conv_w, gamma, (float4*)out, N);
}